// Round 1
// baseline (63.945 us; speedup 1.0000x reference)
//
#include <hip/hip_runtime.h>
#include <hip/hip_bf16.h>

#define PQ 512
#define HH 256
#define WW 256

__global__ __launch_bounds__(PQ) void gs_prep_kernel(
    const float* __restrict__ means, const float* __restrict__ feats,
    const float* __restrict__ opac, const float* __restrict__ scales,
    const float* __restrict__ rots, const float* __restrict__ vm,
    const float* __restrict__ pm, const float* __restrict__ campos,
    const float* __restrict__ tfx, const float* __restrict__ tfy,
    float4* __restrict__ wsA, float4* __restrict__ wsB, float2* __restrict__ wsC)
{
    const int i = threadIdx.x;
    __shared__ float sPx[PQ], sPy[PQ], sNa[PQ], sNb[PQ], sNc[PQ];
    __shared__ float sOp[PQ], sR[PQ], sG[PQ], sBl[PQ], sRm[PQ];
    __shared__ unsigned long long keys[PQ];

    const float mx = means[3*i], my = means[3*i+1], mz = means[3*i+2];
    const float tanfovx = *tfx, tanfovy = *tfy;

    // view transform t = Rv*m + tv
    const float tx = vm[0]*mx + vm[1]*my + vm[2]*mz + vm[3];
    const float ty = vm[4]*mx + vm[5]*my + vm[6]*mz + vm[7];
    const float tz = vm[8]*mx + vm[9]*my + vm[10]*mz + vm[11];
    const float depth = tz;

    // quaternion -> rotation
    float qw = rots[4*i], qx = rots[4*i+1], qy = rots[4*i+2], qz = rots[4*i+3];
    const float qn = 1.0f / sqrtf(qw*qw + qx*qx + qy*qy + qz*qz);
    qw *= qn; qx *= qn; qy *= qn; qz *= qn;
    const float R00 = 1.0f - 2.0f*(qy*qy + qz*qz), R01 = 2.0f*(qx*qy - qw*qz), R02 = 2.0f*(qx*qz + qw*qy);
    const float R10 = 2.0f*(qx*qy + qw*qz), R11 = 1.0f - 2.0f*(qx*qx + qz*qz), R12 = 2.0f*(qy*qz - qw*qx);
    const float R20 = 2.0f*(qx*qz - qw*qy), R21 = 2.0f*(qy*qz + qw*qx), R22 = 1.0f - 2.0f*(qx*qx + qy*qy);

    const float s0 = scales[3*i], s1 = scales[3*i+1], s2 = scales[3*i+2];
    const float Sx = s0*s0, Sy = s1*s1, Sz = s2*s2;
    // cov3 = (R*diag(s)) (R*diag(s))^T
    const float c00 = R00*R00*Sx + R01*R01*Sy + R02*R02*Sz;
    const float c01 = R00*R10*Sx + R01*R11*Sy + R02*R12*Sz;
    const float c02 = R00*R20*Sx + R01*R21*Sy + R02*R22*Sz;
    const float c11 = R10*R10*Sx + R11*R11*Sy + R12*R12*Sz;
    const float c12 = R10*R20*Sx + R11*R21*Sy + R12*R22*Sz;
    const float c22 = R20*R20*Sx + R21*R21*Sy + R22*R22*Sz;

    const float fxs = WW / (2.0f*tanfovx), fys = HH / (2.0f*tanfovy);
    const float limx = 1.3f*tanfovx, limy = 1.3f*tanfovy;
    const float invz = 1.0f / tz;
    const float txz = fminf(fmaxf(tx*invz, -limx), limx) * tz;
    const float tyz = fminf(fmaxf(ty*invz, -limy), limy) * tz;
    const float J00 = fxs*invz, J02 = -fxs*txz*invz*invz;
    const float J11 = fys*invz, J12 = -fys*tyz*invz*invz;
    // T = J @ Rv
    const float T00 = J00*vm[0] + J02*vm[8];
    const float T01 = J00*vm[1] + J02*vm[9];
    const float T02 = J00*vm[2] + J02*vm[10];
    const float T10 = J11*vm[4] + J12*vm[8];
    const float T11 = J11*vm[5] + J12*vm[9];
    const float T12 = J11*vm[6] + J12*vm[10];
    // cov2 = T cov3 T^T
    const float u0 = c00*T00 + c01*T01 + c02*T02;
    const float u1 = c01*T00 + c11*T01 + c12*T02;
    const float u2 = c02*T00 + c12*T01 + c22*T02;
    const float v0 = c00*T10 + c01*T11 + c02*T12;
    const float v1 = c01*T10 + c11*T11 + c12*T12;
    const float v2 = c02*T10 + c12*T11 + c22*T12;
    const float a  = T00*u0 + T01*u1 + T02*u2 + 0.3f;
    const float b  = T10*u0 + T11*u1 + T12*u2;
    const float c  = T10*v0 + T11*v1 + T12*v2 + 0.3f;
    const float det = a*c - b*b;
    const bool valid = (depth > 0.2f) && (det > 0.0f);
    const float inv_det = 1.0f / (det > 0.0f ? det : 1.0f);
    const float ca = c*inv_det, cbq = -b*inv_det, cc = a*inv_det;

    // projection
    const float pw = pm[12]*mx + pm[13]*my + pm[14]*mz + pm[15] + 1e-7f;
    const float p0 = pm[0]*mx + pm[1]*my + pm[2]*mz + pm[3];
    const float p1 = pm[4]*mx + pm[5]*my + pm[6]*mz + pm[7];
    const float px = ((p0/pw + 1.0f)*WW - 1.0f)*0.5f;
    const float py = ((p1/pw + 1.0f)*HH - 1.0f)*0.5f;

    // SH (degree 3)
    const float ddx = mx - campos[0], ddy = my - campos[1], ddz = mz - campos[2];
    const float dn = 1.0f / sqrtf(ddx*ddx + ddy*ddy + ddz*ddz);
    const float x = ddx*dn, y = ddy*dn, z = ddz*dn;
    const float xx = x*x, yy = y*y, zz = z*z, xy = x*y, yz = y*z, xz = x*z;
    const float C0v = 0.28209479177387814f, C1v = 0.4886025119029199f;
    float bas[16];
    bas[0]  = C0v;
    bas[1]  = -C1v*y;  bas[2] = C1v*z;  bas[3] = -C1v*x;
    bas[4]  = 1.0925484305920792f*xy;
    bas[5]  = -1.0925484305920792f*yz;
    bas[6]  = 0.31539156525252005f*(2.0f*zz - xx - yy);
    bas[7]  = -1.0925484305920792f*xz;
    bas[8]  = 0.5462742152960396f*(xx - yy);
    bas[9]  = -0.5900435899266435f*y*(3.0f*xx - yy);
    bas[10] = 2.890611442640554f*xy*z;
    bas[11] = -0.4570457994644658f*y*(4.0f*zz - xx - yy);
    bas[12] = 0.3731763325901154f*z*(2.0f*zz - 3.0f*xx - 3.0f*yy);
    bas[13] = -0.4570457994644658f*x*(4.0f*zz - xx - yy);
    bas[14] = 1.445305721320277f*z*(xx - yy);
    bas[15] = -0.5900435899266435f*x*(xx - 3.0f*yy);
    const float* f = feats + 48*i;
    float col[3];
    #pragma unroll
    for (int ch = 0; ch < 3; ++ch) {
        float r = 0.0f;
        #pragma unroll
        for (int k = 0; k < 16; ++k) r += bas[k] * f[k*3 + ch];
        col[ch] = fmaxf(r + 0.5f, 0.0f);
    }

    const float opa = valid ? opac[i] : 0.0f;

    // conservative skip radius: Q(d) >= lmin*|d|^2 ; skip iff alpha < 1/255 guaranteed
    const float lmin = 0.25f*(ca + cc) - sqrtf(0.0625f*(ca - cc)*(ca - cc) + 0.25f*cbq*cbq);
    const float thr = __logf(255.0f * opa);
    float rmax2;
    if (valid && thr > 0.0f)
        rmax2 = (lmin > 0.0f) ? (thr/lmin)*1.02f + 1e-4f : 3.4e38f;
    else
        rmax2 = 0.0f;

    sPx[i] = px; sPy[i] = py;
    sNa[i] = -0.5f*ca; sNb[i] = -cbq; sNc[i] = -0.5f*cc;
    sOp[i] = opa; sR[i] = col[0]; sG[i] = col[1]; sBl[i] = col[2]; sRm[i] = rmax2;

    // bitonic sort on (depth, idx) ascending — stable via index in low bits
    const unsigned int fb = __float_as_uint(depth);
    const unsigned int ks = fb ^ ((fb >> 31) ? 0xFFFFFFFFu : 0x80000000u);
    keys[i] = ((unsigned long long)ks << 32) | (unsigned int)i;
    __syncthreads();
    for (int k = 2; k <= PQ; k <<= 1) {
        for (int j = k >> 1; j > 0; j >>= 1) {
            const int ixj = i ^ j;
            if (ixj > i) {
                const unsigned long long A_ = keys[i], B_ = keys[ixj];
                const bool up = ((i & k) == 0);
                if ((A_ > B_) == up) { keys[i] = B_; keys[ixj] = A_; }
            }
            __syncthreads();
        }
    }
    const int o = (int)(keys[i] & 0xFFFFFFFFu);
    wsA[i] = make_float4(sPx[o], sPy[o], sRm[o], sNa[o]);
    wsB[i] = make_float4(sNb[o], sNc[o], sOp[o], sR[o]);
    wsC[i] = make_float2(sG[o], sBl[o]);
}

__global__ __launch_bounds__(256) void gs_blend_kernel(
    const float4* __restrict__ wsA, const float4* __restrict__ wsB,
    const float2* __restrict__ wsC, float* __restrict__ out)
{
    __shared__ float4 sA[PQ], sB[PQ];
    __shared__ float2 sC[PQ];
    const int tid = threadIdx.x;
    for (int j = tid; j < PQ; j += 256) { sA[j] = wsA[j]; sB[j] = wsB[j]; sC[j] = wsC[j]; }
    __syncthreads();

    const int pix = blockIdx.x * 256 + tid;
    const float fx = (float)(pix & (WW - 1));
    const float fy = (float)(pix >> 8);

    float T = 1.0f, accr = 0.0f, accg = 0.0f, accb = 0.0f;
    for (int j = 0; j < PQ; ++j) {
        const float4 A = sA[j];
        const float dx = fx - A.x, dy = fy - A.y;
        const float d2 = fmaf(dx, dx, dy*dy);
        if (__all(d2 > A.z)) continue;           // exact conservative cull (alpha < 1/255)
        const float4 B = sB[j];
        const float pwr = A.w*dx*dx + B.x*dx*dy + B.y*dy*dy;
        const float g = __expf(pwr);
        const float al = fminf(0.99f, B.z*g);
        const bool ok = (pwr <= 0.0f) && (al >= (1.0f/255.0f));
        const float w = ok ? al*T : 0.0f;
        const float2 C = sC[j];
        accr = fmaf(w, B.w, accr);
        accg = fmaf(w, C.x, accg);
        accb = fmaf(w, C.y, accb);
        T -= w;
        if (__all(T < 1e-5f)) break;
    }
    out[pix]            = accr + T;   // bg = 1
    out[HH*WW + pix]    = accg + T;
    out[2*HH*WW + pix]  = accb + T;
}

extern "C" void kernel_launch(void* const* d_in, const int* in_sizes, int n_in,
                              void* d_out, int out_size, void* d_ws, size_t ws_size,
                              hipStream_t stream) {
    const float* means  = (const float*)d_in[0];
    const float* feats  = (const float*)d_in[1];
    const float* opac   = (const float*)d_in[2];
    const float* scales = (const float*)d_in[3];
    const float* rots   = (const float*)d_in[4];
    const float* vm     = (const float*)d_in[5];
    const float* pm     = (const float*)d_in[6];
    const float* campos = (const float*)d_in[7];
    const float* tfx    = (const float*)d_in[8];
    const float* tfy    = (const float*)d_in[9];

    float4* wsA = (float4*)d_ws;
    float4* wsB = wsA + PQ;
    float2* wsC = (float2*)(wsB + PQ);

    gs_prep_kernel<<<1, PQ, 0, stream>>>(means, feats, opac, scales, rots, vm, pm,
                                         campos, tfx, tfy, wsA, wsB, wsC);
    gs_blend_kernel<<<(HH*WW)/256, 256, 0, stream>>>(wsA, wsB, wsC, (float*)d_out);
}

// Round 2
// 21.352 us; speedup vs baseline: 2.9948x; 2.9948x over previous
//
#include <hip/hip_runtime.h>
#include <hip/hip_bf16.h>

#define PQ 512
#define HH 256
#define WW 256

__global__ __launch_bounds__(PQ) void gs_prep_kernel(
    const float* __restrict__ means, const float* __restrict__ feats,
    const float* __restrict__ opac, const float* __restrict__ scales,
    const float* __restrict__ rots, const float* __restrict__ vm,
    const float* __restrict__ pm, const float* __restrict__ campos,
    const float* __restrict__ tfx, const float* __restrict__ tfy,
    float4* __restrict__ wsA, float4* __restrict__ wsB, float2* __restrict__ wsC)
{
    const int i = threadIdx.x;
    __shared__ float sPx[PQ], sPy[PQ], sNa[PQ], sNb[PQ], sNc[PQ];
    __shared__ float sOp[PQ], sR[PQ], sG[PQ], sBl[PQ], sRm[PQ];
    __shared__ unsigned long long keys[PQ];

    const float mx = means[3*i], my = means[3*i+1], mz = means[3*i+2];
    const float tanfovx = *tfx, tanfovy = *tfy;

    // view transform t = Rv*m + tv
    const float tx = vm[0]*mx + vm[1]*my + vm[2]*mz + vm[3];
    const float ty = vm[4]*mx + vm[5]*my + vm[6]*mz + vm[7];
    const float tz = vm[8]*mx + vm[9]*my + vm[10]*mz + vm[11];
    const float depth = tz;

    // quaternion -> rotation
    float qw = rots[4*i], qx = rots[4*i+1], qy = rots[4*i+2], qz = rots[4*i+3];
    const float qn = 1.0f / sqrtf(qw*qw + qx*qx + qy*qy + qz*qz);
    qw *= qn; qx *= qn; qy *= qn; qz *= qn;
    const float R00 = 1.0f - 2.0f*(qy*qy + qz*qz), R01 = 2.0f*(qx*qy - qw*qz), R02 = 2.0f*(qx*qz + qw*qy);
    const float R10 = 2.0f*(qx*qy + qw*qz), R11 = 1.0f - 2.0f*(qx*qx + qz*qz), R12 = 2.0f*(qy*qz - qw*qx);
    const float R20 = 2.0f*(qx*qz - qw*qy), R21 = 2.0f*(qy*qz + qw*qx), R22 = 1.0f - 2.0f*(qx*qx + qy*qy);

    const float s0 = scales[3*i], s1 = scales[3*i+1], s2 = scales[3*i+2];
    const float Sx = s0*s0, Sy = s1*s1, Sz = s2*s2;
    const float c00 = R00*R00*Sx + R01*R01*Sy + R02*R02*Sz;
    const float c01 = R00*R10*Sx + R01*R11*Sy + R02*R12*Sz;
    const float c02 = R00*R20*Sx + R01*R21*Sy + R02*R22*Sz;
    const float c11 = R10*R10*Sx + R11*R11*Sy + R12*R12*Sz;
    const float c12 = R10*R20*Sx + R11*R21*Sy + R12*R22*Sz;
    const float c22 = R20*R20*Sx + R21*R21*Sy + R22*R22*Sz;

    const float fxs = WW / (2.0f*tanfovx), fys = HH / (2.0f*tanfovy);
    const float limx = 1.3f*tanfovx, limy = 1.3f*tanfovy;
    const float invz = 1.0f / tz;
    const float txz = fminf(fmaxf(tx*invz, -limx), limx) * tz;
    const float tyz = fminf(fmaxf(ty*invz, -limy), limy) * tz;
    const float J00 = fxs*invz, J02 = -fxs*txz*invz*invz;
    const float J11 = fys*invz, J12 = -fys*tyz*invz*invz;
    const float T00 = J00*vm[0] + J02*vm[8];
    const float T01 = J00*vm[1] + J02*vm[9];
    const float T02 = J00*vm[2] + J02*vm[10];
    const float T10 = J11*vm[4] + J12*vm[8];
    const float T11 = J11*vm[5] + J12*vm[9];
    const float T12 = J11*vm[6] + J12*vm[10];
    const float u0 = c00*T00 + c01*T01 + c02*T02;
    const float u1 = c01*T00 + c11*T01 + c12*T02;
    const float u2 = c02*T00 + c12*T01 + c22*T02;
    const float v0 = c00*T10 + c01*T11 + c02*T12;
    const float v1 = c01*T10 + c11*T11 + c12*T12;
    const float v2 = c02*T10 + c12*T11 + c22*T12;
    const float a  = T00*u0 + T01*u1 + T02*u2 + 0.3f;
    const float b  = T10*u0 + T11*u1 + T12*u2;
    const float c  = T10*v0 + T11*v1 + T12*v2 + 0.3f;
    const float det = a*c - b*b;
    const bool valid = (depth > 0.2f) && (det > 0.0f);
    const float inv_det = 1.0f / (det > 0.0f ? det : 1.0f);
    const float ca = c*inv_det, cbq = -b*inv_det, cc = a*inv_det;

    // projection
    const float pw = pm[12]*mx + pm[13]*my + pm[14]*mz + pm[15] + 1e-7f;
    const float p0 = pm[0]*mx + pm[1]*my + pm[2]*mz + pm[3];
    const float p1 = pm[4]*mx + pm[5]*my + pm[6]*mz + pm[7];
    const float px = ((p0/pw + 1.0f)*WW - 1.0f)*0.5f;
    const float py = ((p1/pw + 1.0f)*HH - 1.0f)*0.5f;

    // SH (degree 3)
    const float ddx = mx - campos[0], ddy = my - campos[1], ddz = mz - campos[2];
    const float dn = 1.0f / sqrtf(ddx*ddx + ddy*ddy + ddz*ddz);
    const float x = ddx*dn, y = ddy*dn, z = ddz*dn;
    const float xx = x*x, yy = y*y, zz = z*z, xy = x*y, yz = y*z, xz = x*z;
    const float C0v = 0.28209479177387814f, C1v = 0.4886025119029199f;
    float bas[16];
    bas[0]  = C0v;
    bas[1]  = -C1v*y;  bas[2] = C1v*z;  bas[3] = -C1v*x;
    bas[4]  = 1.0925484305920792f*xy;
    bas[5]  = -1.0925484305920792f*yz;
    bas[6]  = 0.31539156525252005f*(2.0f*zz - xx - yy);
    bas[7]  = -1.0925484305920792f*xz;
    bas[8]  = 0.5462742152960396f*(xx - yy);
    bas[9]  = -0.5900435899266435f*y*(3.0f*xx - yy);
    bas[10] = 2.890611442640554f*xy*z;
    bas[11] = -0.4570457994644658f*y*(4.0f*zz - xx - yy);
    bas[12] = 0.3731763325901154f*z*(2.0f*zz - 3.0f*xx - 3.0f*yy);
    bas[13] = -0.4570457994644658f*x*(4.0f*zz - xx - yy);
    bas[14] = 1.445305721320277f*z*(xx - yy);
    bas[15] = -0.5900435899266435f*x*(xx - 3.0f*yy);
    const float* f = feats + 48*i;
    float col[3];
    #pragma unroll
    for (int ch = 0; ch < 3; ++ch) {
        float r = 0.0f;
        #pragma unroll
        for (int k = 0; k < 16; ++k) r += bas[k] * f[k*3 + ch];
        col[ch] = fmaxf(r + 0.5f, 0.0f);
    }

    const float opa = valid ? opac[i] : 0.0f;

    // conservative skip radius
    const float lmin = 0.25f*(ca + cc) - sqrtf(0.0625f*(ca - cc)*(ca - cc) + 0.25f*cbq*cbq);
    const float thr = __logf(255.0f * opa);
    float rmax2;
    if (valid && thr > 0.0f)
        rmax2 = (lmin > 0.0f) ? (thr/lmin)*1.02f + 1e-4f : 3.4e38f;
    else
        rmax2 = 0.0f;

    sPx[i] = px; sPy[i] = py;
    sNa[i] = -0.5f*ca; sNb[i] = -cbq; sNc[i] = -0.5f*cc;
    sOp[i] = opa; sR[i] = col[0]; sG[i] = col[1]; sBl[i] = col[2]; sRm[i] = rmax2;

    // bitonic sort on (depth, idx)
    const unsigned int fb = __float_as_uint(depth);
    const unsigned int ks = fb ^ ((fb >> 31) ? 0xFFFFFFFFu : 0x80000000u);
    keys[i] = ((unsigned long long)ks << 32) | (unsigned int)i;
    __syncthreads();
    for (int k = 2; k <= PQ; k <<= 1) {
        for (int j = k >> 1; j > 0; j >>= 1) {
            const int ixj = i ^ j;
            if (ixj > i) {
                const unsigned long long A_ = keys[i], B_ = keys[ixj];
                const bool up = ((i & k) == 0);
                if ((A_ > B_) == up) { keys[i] = B_; keys[ixj] = A_; }
            }
            __syncthreads();
        }
    }
    const int o = (int)(keys[i] & 0xFFFFFFFFu);
    wsA[i] = make_float4(sPx[o], sPy[o], sRm[o], sNa[o]);
    wsB[i] = make_float4(sNb[o], sNc[o], sOp[o], sR[o]);
    wsC[i] = make_float2(sG[o], sBl[o]);
}

// One block per image row. Phase 1: depth-ordered compaction of gaussians
// that can touch this row (conservative dy^2 <= rmax^2 cull — only removes
// gaussians with alpha < 1/255 everywhere in the row, which the reference
// zeroes too). Phase 2: branch-free blend over the compacted list.
__global__ __launch_bounds__(256) void gs_blend_kernel(
    const float4* __restrict__ wsA, const float4* __restrict__ wsB,
    const float2* __restrict__ wsC, float* __restrict__ out)
{
    __shared__ float4 LA[PQ], LB[PQ];
    __shared__ float2 LC[PQ];
    __shared__ int s_cnt[4];
    __shared__ int s_base[5];

    const int tid  = threadIdx.x;
    const int wid  = tid >> 6;
    const int lane = tid & 63;
    const int row  = blockIdx.x;
    const float fy = (float)row;

    // phase 1a: test 128 gaussians per wave (contiguous chunk keeps depth order)
    float4 Areg[2];
    bool keepf[2];
    unsigned long long mask[2];
    int cnt = 0;
    #pragma unroll
    for (int r = 0; r < 2; ++r) {
        const int j = wid*128 + r*64 + lane;
        const float4 A = wsA[j];
        const float dy = fy - A.y;
        const bool k = (dy*dy <= A.z);
        Areg[r] = A; keepf[r] = k;
        mask[r] = __ballot(k);
        cnt += __popcll(mask[r]);
    }
    if (lane == 0) s_cnt[wid] = cnt;
    __syncthreads();
    if (tid == 0) {
        int s = 0;
        #pragma unroll
        for (int w = 0; w < 4; ++w) { s_base[w] = s; s += s_cnt[w]; }
        s_base[4] = s;
    }
    __syncthreads();

    // phase 1b: scatter survivors into LDS at compacted (depth-ordered) slots
    int pos = s_base[wid];
    #pragma unroll
    for (int r = 0; r < 2; ++r) {
        const int j = wid*128 + r*64 + lane;
        if (keepf[r]) {
            const int p = pos + __popcll(mask[r] & ((1ULL << lane) - 1ULL));
            LA[p] = Areg[r];
            LB[p] = wsB[j];
            LC[p] = wsC[j];
        }
        pos += __popcll(mask[r]);
    }
    __syncthreads();

    // phase 2: branch-free front-to-back blend (LDS broadcasts, pipelineable)
    const int n = s_base[4];
    const float fx = (float)tid;
    float T = 1.0f, accr = 0.0f, accg = 0.0f, accb = 0.0f;
    for (int j = 0; j < n; ++j) {
        const float4 A = LA[j];
        const float4 B = LB[j];
        const float2 C = LC[j];
        const float dx = fx - A.x, dy = fy - A.y;
        const float pwr = A.w*dx*dx + B.x*dx*dy + B.y*dy*dy;
        const float g = __expf(pwr);
        const float al = fminf(0.99f, B.z*g);
        const bool ok = (pwr <= 0.0f) && (al >= (1.0f/255.0f));
        const float w = ok ? al*T : 0.0f;
        accr = fmaf(w, B.w, accr);
        accg = fmaf(w, C.x, accg);
        accb = fmaf(w, C.y, accb);
        T -= w;
    }

    const int pix = row*WW + tid;
    out[pix]            = accr + T;   // bg = 1
    out[HH*WW + pix]    = accg + T;
    out[2*HH*WW + pix]  = accb + T;
}

extern "C" void kernel_launch(void* const* d_in, const int* in_sizes, int n_in,
                              void* d_out, int out_size, void* d_ws, size_t ws_size,
                              hipStream_t stream) {
    const float* means  = (const float*)d_in[0];
    const float* feats  = (const float*)d_in[1];
    const float* opac   = (const float*)d_in[2];
    const float* scales = (const float*)d_in[3];
    const float* rots   = (const float*)d_in[4];
    const float* vm     = (const float*)d_in[5];
    const float* pm     = (const float*)d_in[6];
    const float* campos = (const float*)d_in[7];
    const float* tfx    = (const float*)d_in[8];
    const float* tfy    = (const float*)d_in[9];

    float4* wsA = (float4*)d_ws;
    float4* wsB = wsA + PQ;
    float2* wsC = (float2*)(wsB + PQ);

    gs_prep_kernel<<<1, PQ, 0, stream>>>(means, feats, opac, scales, rots, vm, pm,
                                         campos, tfx, tfy, wsA, wsB, wsC);
    gs_blend_kernel<<<(HH*WW)/WW, 256, 0, stream>>>(wsA, wsB, wsC, (float*)d_out);
}

// Round 6
// 13.511 us; speedup vs baseline: 4.7329x; 1.5804x over previous
//
#include <hip/hip_runtime.h>
#include <hip/hip_bf16.h>

#define PQ 512
#define HH 256
#define WW 256

// One block per image row; each block redundantly preprocesses all P=512
// gaussians (parallel across 256 CUs), culls to the row's survivor set
// (conservative: only drops gaussians with alpha < 1/255 for every pixel in
// the row, which the reference also zeroes), rank-sorts survivors by the
// global (depth,idx) key (exact match to stable argsort), computes SH for
// survivors only, then does a branch-free front-to-back blend.
__global__ __launch_bounds__(256) void gs_fused_kernel(
    const float* __restrict__ means, const float* __restrict__ feats,
    const float* __restrict__ opac, const float* __restrict__ scales,
    const float* __restrict__ rots, const float* __restrict__ vm,
    const float* __restrict__ pm, const float* __restrict__ campos,
    const float* __restrict__ tfx, const float* __restrict__ tfy,
    float* __restrict__ out)
{
    __shared__ unsigned long long cKey[PQ];
    __shared__ int   cGi[PQ];
    __shared__ float cPx[PQ], cNa[PQ], cU[PQ], cV[PQ], cOp[PQ];
    __shared__ float4 SA[PQ], SB[PQ];
    __shared__ int s_cnt[4], s_base[5];

    const int tid  = threadIdx.x;
    const int wid  = tid >> 6;
    const int lane = tid & 63;
    const float fy = (float)blockIdx.x;

    const float tanfovx = *tfx, tanfovy = *tfy;
    const float fxs = WW / (2.0f*tanfovx), fys = HH / (2.0f*tanfovy);
    const float limx = 1.3f*tanfovx, limy = 1.3f*tanfovy;

    // ---------------- phase A: per-gaussian geometry + row cull ----------------
    float rPx[2], rNa[2], rU[2], rV[2], rOp[2];
    unsigned long long rKey[2], m[2];
    bool kp[2];
    int cnt = 0;

    #pragma unroll
    for (int r = 0; r < 2; ++r) {
        const int g = r*256 + tid;
        const float mx = means[3*g], my = means[3*g+1], mz = means[3*g+2];

        // view transform
        const float tx = vm[0]*mx + vm[1]*my + vm[2]*mz + vm[3];
        const float ty = vm[4]*mx + vm[5]*my + vm[6]*mz + vm[7];
        const float tz = vm[8]*mx + vm[9]*my + vm[10]*mz + vm[11];
        const float depth = tz;

        // quaternion -> rotation
        const float4 q = *reinterpret_cast<const float4*>(rots + 4*g);
        float qw = q.x, qx = q.y, qy = q.z, qz = q.w;
        const float qn = 1.0f / sqrtf(qw*qw + qx*qx + qy*qy + qz*qz);
        qw *= qn; qx *= qn; qy *= qn; qz *= qn;
        const float R00 = 1.0f - 2.0f*(qy*qy + qz*qz), R01 = 2.0f*(qx*qy - qw*qz), R02 = 2.0f*(qx*qz + qw*qy);
        const float R10 = 2.0f*(qx*qy + qw*qz), R11 = 1.0f - 2.0f*(qx*qx + qz*qz), R12 = 2.0f*(qy*qz - qw*qx);
        const float R20 = 2.0f*(qx*qz - qw*qy), R21 = 2.0f*(qy*qz + qw*qx), R22 = 1.0f - 2.0f*(qx*qx + qy*qy);

        const float s0 = scales[3*g], s1 = scales[3*g+1], s2 = scales[3*g+2];
        const float Sx = s0*s0, Sy = s1*s1, Sz = s2*s2;
        const float c00 = R00*R00*Sx + R01*R01*Sy + R02*R02*Sz;
        const float c01 = R00*R10*Sx + R01*R11*Sy + R02*R12*Sz;
        const float c02 = R00*R20*Sx + R01*R21*Sy + R02*R22*Sz;
        const float c11 = R10*R10*Sx + R11*R11*Sy + R12*R12*Sz;
        const float c12 = R10*R20*Sx + R11*R21*Sy + R12*R22*Sz;
        const float c22 = R20*R20*Sx + R21*R21*Sy + R22*R22*Sz;

        const float invz = 1.0f / tz;
        const float txz = fminf(fmaxf(tx*invz, -limx), limx) * tz;
        const float tyz = fminf(fmaxf(ty*invz, -limy), limy) * tz;
        const float J00 = fxs*invz, J02 = -fxs*txz*invz*invz;
        const float J11 = fys*invz, J12 = -fys*tyz*invz*invz;
        const float T00 = J00*vm[0] + J02*vm[8];
        const float T01 = J00*vm[1] + J02*vm[9];
        const float T02 = J00*vm[2] + J02*vm[10];
        const float T10 = J11*vm[4] + J12*vm[8];
        const float T11 = J11*vm[5] + J12*vm[9];
        const float T12 = J11*vm[6] + J12*vm[10];
        const float u0 = c00*T00 + c01*T01 + c02*T02;
        const float u1 = c01*T00 + c11*T01 + c12*T02;
        const float u2 = c02*T00 + c12*T01 + c22*T02;
        const float v0 = c00*T10 + c01*T11 + c02*T12;
        const float v1 = c01*T10 + c11*T11 + c12*T12;
        const float v2 = c02*T10 + c12*T11 + c22*T12;
        const float a  = T00*u0 + T01*u1 + T02*u2 + 0.3f;
        const float b  = T10*u0 + T11*u1 + T12*u2;
        const float c  = T10*v0 + T11*v1 + T12*v2 + 0.3f;
        const float det = a*c - b*b;
        const bool valid = (depth > 0.2f) && (det > 0.0f);
        const float inv_det = 1.0f / (det > 0.0f ? det : 1.0f);
        const float ca = c*inv_det, cbq = -b*inv_det, cc = a*inv_det;

        // projection
        const float pw = pm[12]*mx + pm[13]*my + pm[14]*mz + pm[15] + 1e-7f;
        const float p0 = pm[0]*mx + pm[1]*my + pm[2]*mz + pm[3];
        const float p1 = pm[4]*mx + pm[5]*my + pm[6]*mz + pm[7];
        const float px = ((p0/pw + 1.0f)*WW - 1.0f)*0.5f;
        const float py = ((p1/pw + 1.0f)*HH - 1.0f)*0.5f;

        const float opa_ = valid ? opac[g] : 0.0f;

        // conservative skip radius (alpha < 1/255 guaranteed outside rmax2)
        const float lmin = 0.25f*(ca + cc) - sqrtf(0.0625f*(ca - cc)*(ca - cc) + 0.25f*cbq*cbq);
        const float thr = __logf(255.0f * opa_);
        float rmax2;
        if (valid && thr > 0.0f)
            rmax2 = (lmin > 0.0f) ? (thr/lmin)*1.02f + 1e-4f : 3.4e38f;
        else
            rmax2 = 0.0f;

        // row cull: min over row pixels of |d|^2 = dy^2 + dxn^2
        const float dy  = fy - py;
        const float dxn = fmaxf(0.0f, fmaxf(-px, px - (float)(WW-1)));
        kp[r] = (fmaf(dy, dy, dxn*dxn) <= rmax2);

        rPx[r] = px;
        rNa[r] = -0.5f*ca;
        rU[r]  = -cbq*dy;           // nb*dy
        rV[r]  = (-0.5f*cc)*dy*dy;  // nc*dy^2
        rOp[r] = opa_;

        const unsigned int fb = __float_as_uint(depth);
        const unsigned int ks = fb ^ ((fb >> 31) ? 0xFFFFFFFFu : 0x80000000u);
        rKey[r] = ((unsigned long long)ks << 32) | (unsigned int)g;

        m[r] = __ballot(kp[r]);
        cnt += __popcll(m[r]);
    }

    if (lane == 0) s_cnt[wid] = cnt;
    __syncthreads();
    if (tid == 0) {
        int s = 0;
        #pragma unroll
        for (int w = 0; w < 4; ++w) { s_base[w] = s; s += s_cnt[w]; }
        s_base[4] = s;
    }
    __syncthreads();

    // scatter survivors (order irrelevant — sorted next; positions deterministic)
    int pos = s_base[wid];
    #pragma unroll
    for (int r = 0; r < 2; ++r) {
        if (kp[r]) {
            const int p = pos + __popcll(m[r] & ((1ULL << lane) - 1ULL));
            cKey[p] = rKey[r]; cGi[p] = r*256 + tid;
            cPx[p] = rPx[r]; cNa[p] = rNa[r]; cU[p] = rU[r]; cV[p] = rV[r]; cOp[p] = rOp[r];
        }
        pos += __popcll(m[r]);
    }
    __syncthreads();

    const int n = s_base[4];

    // ------------- phase B: rank-sort survivors + SH for survivors only -------------
    for (int j = tid; j < n; j += 256) {
        const unsigned long long kj = cKey[j];
        int rk = 0;
        for (int i = 0; i < n; ++i) rk += (cKey[i] < kj) ? 1 : 0;

        const int g = cGi[j];
        const float mx = means[3*g], my = means[3*g+1], mz = means[3*g+2];
        const float ddx = mx - campos[0], ddy = my - campos[1], ddz = mz - campos[2];
        const float dn = 1.0f / sqrtf(ddx*ddx + ddy*ddy + ddz*ddz);
        const float x = ddx*dn, y = ddy*dn, z = ddz*dn;
        const float xx = x*x, yy = y*y, zz = z*z, xy = x*y, yz = y*z, xz = x*z;
        float bas[16];
        bas[0]  = 0.28209479177387814f;
        bas[1]  = -0.4886025119029199f*y;
        bas[2]  = 0.4886025119029199f*z;
        bas[3]  = -0.4886025119029199f*x;
        bas[4]  = 1.0925484305920792f*xy;
        bas[5]  = -1.0925484305920792f*yz;
        bas[6]  = 0.31539156525252005f*(2.0f*zz - xx - yy);
        bas[7]  = -1.0925484305920792f*xz;
        bas[8]  = 0.5462742152960396f*(xx - yy);
        bas[9]  = -0.5900435899266435f*y*(3.0f*xx - yy);
        bas[10] = 2.890611442640554f*xy*z;
        bas[11] = -0.4570457994644658f*y*(4.0f*zz - xx - yy);
        bas[12] = 0.3731763325901154f*z*(2.0f*zz - 3.0f*xx - 3.0f*yy);
        bas[13] = -0.4570457994644658f*x*(4.0f*zz - xx - yy);
        bas[14] = 1.445305721320277f*z*(xx - yy);
        bas[15] = -0.5900435899266435f*x*(xx - 3.0f*yy);

        float fv[48];
        const float4* fp = reinterpret_cast<const float4*>(feats + 48*g);
        #pragma unroll
        for (int qq = 0; qq < 12; ++qq)
            *reinterpret_cast<float4*>(&fv[4*qq]) = fp[qq];

        float colr = 0.0f, colg = 0.0f, colb = 0.0f;
        #pragma unroll
        for (int k = 0; k < 16; ++k) {
            colr += bas[k]*fv[k*3+0];
            colg += bas[k]*fv[k*3+1];
            colb += bas[k]*fv[k*3+2];
        }
        colr = fmaxf(colr + 0.5f, 0.0f);
        colg = fmaxf(colg + 0.5f, 0.0f);
        colb = fmaxf(colb + 0.5f, 0.0f);

        SA[rk] = make_float4(cPx[j], cNa[j], cU[j], cV[j]);
        SB[rk] = make_float4(cOp[j], colr, colg, colb);
    }
    __syncthreads();

    // ---------------- phase C: branch-free front-to-back blend ----------------
    const float fx = (float)tid;
    float T = 1.0f, accr = 0.0f, accg = 0.0f, accb = 0.0f;
    #pragma unroll 4
    for (int j = 0; j < n; ++j) {
        const float4 A = SA[j];
        const float4 B = SB[j];
        const float dx  = fx - A.x;
        const float pwr = fmaf(fmaf(A.y, dx, A.z), dx, A.w);
        const float gg  = __expf(pwr);
        const float al  = fminf(0.99f, B.x*gg);
        const bool  ok  = (pwr <= 0.0f) && (al >= (1.0f/255.0f));
        const float w   = ok ? al*T : 0.0f;
        accr = fmaf(w, B.y, accr);
        accg = fmaf(w, B.z, accg);
        accb = fmaf(w, B.w, accb);
        T -= w;
    }

    const int pix = blockIdx.x*WW + tid;
    out[pix]            = accr + T;   // bg = 1
    out[HH*WW + pix]    = accg + T;
    out[2*HH*WW + pix]  = accb + T;
}

extern "C" void kernel_launch(void* const* d_in, const int* in_sizes, int n_in,
                              void* d_out, int out_size, void* d_ws, size_t ws_size,
                              hipStream_t stream) {
    const float* means  = (const float*)d_in[0];
    const float* feats  = (const float*)d_in[1];
    const float* opac   = (const float*)d_in[2];
    const float* scales = (const float*)d_in[3];
    const float* rots   = (const float*)d_in[4];
    const float* vm     = (const float*)d_in[5];
    const float* pm     = (const float*)d_in[6];
    const float* campos = (const float*)d_in[7];
    const float* tfx    = (const float*)d_in[8];
    const float* tfy    = (const float*)d_in[9];

    gs_fused_kernel<<<HH, 256, 0, stream>>>(means, feats, opac, scales, rots, vm, pm,
                                            campos, tfx, tfy, (float*)d_out);
}

// Round 9
// 12.010 us; speedup vs baseline: 5.3242x; 1.1249x over previous
//
#include <hip/hip_runtime.h>
#include <hip/hip_bf16.h>

#define PQ 512
#define HH 256
#define WW 256

// One block per image row, 1024 threads (16 waves/CU).
// Phase A: 1 gaussian/thread geometry + conservative row cull (only drops
//   gaussians with alpha < 1/255 across the whole row) + ballot compaction.
// Phase B: rank-sort survivors by global (depth,idx) key (exact stable
//   argsort match) + SH eval for survivors only.
// Phase C: 4-way depth-segmented blend — thread-group q blends sorted
//   quarter q for its pixel; partials combined via T-products in LDS
//   (front-to-back compositing is associative).
__global__ __launch_bounds__(1024) void gs_fused_kernel(
    const float* __restrict__ means, const float* __restrict__ feats,
    const float* __restrict__ opac, const float* __restrict__ scales,
    const float* __restrict__ rots, const float* __restrict__ vm,
    const float* __restrict__ pm, const float* __restrict__ campos,
    const float* __restrict__ tfx, const float* __restrict__ tfy,
    float* __restrict__ out)
{
    __shared__ unsigned long long cKey[PQ];
    __shared__ int   cGi[PQ];
    __shared__ float cPx[PQ], cNa[PQ], cU[PQ], cV[PQ], cOp[PQ];
    __shared__ float4 SA[PQ], SB[PQ];
    __shared__ float4 comb[4][WW];
    __shared__ int s_cnt[8], s_base[9];

    const int tid  = threadIdx.x;
    const int wid  = tid >> 6;
    const int lane = tid & 63;
    const float fy = (float)blockIdx.x;

    const float tanfovx = *tfx, tanfovy = *tfy;
    const float fxs = WW / (2.0f*tanfovx), fys = HH / (2.0f*tanfovy);
    const float limx = 1.3f*tanfovx, limy = 1.3f*tanfovy;

    // ---------------- phase A: per-gaussian geometry + row cull ----------------
    float rPx = 0.f, rNa = 0.f, rU = 0.f, rV = 0.f, rOp = 0.f;
    unsigned long long rKey = 0, m = 0;
    bool kp = false;

    if (tid < PQ) {                       // waves 0..7, wave-uniform branch
        const int g = tid;
        const float mx = means[3*g], my = means[3*g+1], mz = means[3*g+2];

        // view transform
        const float tx = vm[0]*mx + vm[1]*my + vm[2]*mz + vm[3];
        const float ty = vm[4]*mx + vm[5]*my + vm[6]*mz + vm[7];
        const float tz = vm[8]*mx + vm[9]*my + vm[10]*mz + vm[11];
        const float depth = tz;

        // quaternion -> rotation
        const float4 q = *reinterpret_cast<const float4*>(rots + 4*g);
        float qw = q.x, qx = q.y, qy = q.z, qz = q.w;
        const float qn = 1.0f / sqrtf(qw*qw + qx*qx + qy*qy + qz*qz);
        qw *= qn; qx *= qn; qy *= qn; qz *= qn;
        const float R00 = 1.0f - 2.0f*(qy*qy + qz*qz), R01 = 2.0f*(qx*qy - qw*qz), R02 = 2.0f*(qx*qz + qw*qy);
        const float R10 = 2.0f*(qx*qy + qw*qz), R11 = 1.0f - 2.0f*(qx*qx + qz*qz), R12 = 2.0f*(qy*qz - qw*qx);
        const float R20 = 2.0f*(qx*qz - qw*qy), R21 = 2.0f*(qy*qz + qw*qx), R22 = 1.0f - 2.0f*(qx*qx + qy*qy);

        const float s0 = scales[3*g], s1 = scales[3*g+1], s2 = scales[3*g+2];
        const float Sx = s0*s0, Sy = s1*s1, Sz = s2*s2;
        const float c00 = R00*R00*Sx + R01*R01*Sy + R02*R02*Sz;
        const float c01 = R00*R10*Sx + R01*R11*Sy + R02*R12*Sz;
        const float c02 = R00*R20*Sx + R01*R21*Sy + R02*R22*Sz;
        const float c11 = R10*R10*Sx + R11*R11*Sy + R12*R12*Sz;
        const float c12 = R10*R20*Sx + R11*R21*Sy + R12*R22*Sz;
        const float c22 = R20*R20*Sx + R21*R21*Sy + R22*R22*Sz;

        const float invz = 1.0f / tz;
        const float txz = fminf(fmaxf(tx*invz, -limx), limx) * tz;
        const float tyz = fminf(fmaxf(ty*invz, -limy), limy) * tz;
        const float J00 = fxs*invz, J02 = -fxs*txz*invz*invz;
        const float J11 = fys*invz, J12 = -fys*tyz*invz*invz;
        const float T00 = J00*vm[0] + J02*vm[8];
        const float T01 = J00*vm[1] + J02*vm[9];
        const float T02 = J00*vm[2] + J02*vm[10];
        const float T10 = J11*vm[4] + J12*vm[8];
        const float T11 = J11*vm[5] + J12*vm[9];
        const float T12 = J11*vm[6] + J12*vm[10];
        const float u0 = c00*T00 + c01*T01 + c02*T02;
        const float u1 = c01*T00 + c11*T01 + c12*T02;
        const float u2 = c02*T00 + c12*T01 + c22*T02;
        const float v0 = c00*T10 + c01*T11 + c02*T12;
        const float v1 = c01*T10 + c11*T11 + c12*T12;
        const float v2 = c02*T10 + c12*T11 + c22*T12;
        const float a  = T00*u0 + T01*u1 + T02*u2 + 0.3f;
        const float b  = T10*u0 + T11*u1 + T12*u2;
        const float c  = T10*v0 + T11*v1 + T12*v2 + 0.3f;
        const float det = a*c - b*b;
        const bool valid = (depth > 0.2f) && (det > 0.0f);
        const float inv_det = 1.0f / (det > 0.0f ? det : 1.0f);
        const float ca = c*inv_det, cbq = -b*inv_det, cc = a*inv_det;

        // projection
        const float pw = pm[12]*mx + pm[13]*my + pm[14]*mz + pm[15] + 1e-7f;
        const float p0 = pm[0]*mx + pm[1]*my + pm[2]*mz + pm[3];
        const float p1 = pm[4]*mx + pm[5]*my + pm[6]*mz + pm[7];
        const float px = ((p0/pw + 1.0f)*WW - 1.0f)*0.5f;
        const float py = ((p1/pw + 1.0f)*HH - 1.0f)*0.5f;

        const float opa_ = valid ? opac[g] : 0.0f;

        // conservative skip radius (alpha < 1/255 guaranteed outside rmax2)
        const float lmin = 0.25f*(ca + cc) - sqrtf(0.0625f*(ca - cc)*(ca - cc) + 0.25f*cbq*cbq);
        const float thr = __logf(255.0f * opa_);
        float rmax2;
        if (valid && thr > 0.0f)
            rmax2 = (lmin > 0.0f) ? (thr/lmin)*1.02f + 1e-4f : 3.4e38f;
        else
            rmax2 = 0.0f;

        // row cull
        const float dy  = fy - py;
        const float dxn = fmaxf(0.0f, fmaxf(-px, px - (float)(WW-1)));
        kp = (fmaf(dy, dy, dxn*dxn) <= rmax2);

        rPx = px;
        rNa = -0.5f*ca;
        rU  = -cbq*dy;           // nb*dy
        rV  = (-0.5f*cc)*dy*dy;  // nc*dy^2
        rOp = opa_;

        const unsigned int fb = __float_as_uint(depth);
        const unsigned int ks = fb ^ ((fb >> 31) ? 0xFFFFFFFFu : 0x80000000u);
        rKey = ((unsigned long long)ks << 32) | (unsigned int)g;

        m = __ballot(kp);
        if (lane == 0) s_cnt[wid] = __popcll(m);
    }
    __syncthreads();
    if (tid == 0) {
        int s = 0;
        #pragma unroll
        for (int w = 0; w < 8; ++w) { s_base[w] = s; s += s_cnt[w]; }
        s_base[8] = s;
    }
    __syncthreads();

    // scatter survivors into compacted LDS slots
    if (tid < PQ && kp) {
        const int p = s_base[wid] + __popcll(m & ((1ULL << lane) - 1ULL));
        cKey[p] = rKey; cGi[p] = tid;
        cPx[p] = rPx; cNa[p] = rNa; cU[p] = rU; cV[p] = rV; cOp[p] = rOp;
    }
    __syncthreads();

    const int n = s_base[8];

    // ------------- phase B: rank-sort survivors + SH for survivors only -------------
    if (tid < n) {
        const int j = tid;
        const unsigned long long kj = cKey[j];
        int rk = 0;
        for (int i = 0; i < n; ++i) rk += (cKey[i] < kj) ? 1 : 0;

        const int g = cGi[j];
        const float mx = means[3*g], my = means[3*g+1], mz = means[3*g+2];
        const float ddx = mx - campos[0], ddy = my - campos[1], ddz = mz - campos[2];
        const float dn = 1.0f / sqrtf(ddx*ddx + ddy*ddy + ddz*ddz);
        const float x = ddx*dn, y = ddy*dn, z = ddz*dn;
        const float xx = x*x, yy = y*y, zz = z*z, xy = x*y, yz = y*z, xz = x*z;
        float bas[16];
        bas[0]  = 0.28209479177387814f;
        bas[1]  = -0.4886025119029199f*y;
        bas[2]  = 0.4886025119029199f*z;
        bas[3]  = -0.4886025119029199f*x;
        bas[4]  = 1.0925484305920792f*xy;
        bas[5]  = -1.0925484305920792f*yz;
        bas[6]  = 0.31539156525252005f*(2.0f*zz - xx - yy);
        bas[7]  = -1.0925484305920792f*xz;
        bas[8]  = 0.5462742152960396f*(xx - yy);
        bas[9]  = -0.5900435899266435f*y*(3.0f*xx - yy);
        bas[10] = 2.890611442640554f*xy*z;
        bas[11] = -0.4570457994644658f*y*(4.0f*zz - xx - yy);
        bas[12] = 0.3731763325901154f*z*(2.0f*zz - 3.0f*xx - 3.0f*yy);
        bas[13] = -0.4570457994644658f*x*(4.0f*zz - xx - yy);
        bas[14] = 1.445305721320277f*z*(xx - yy);
        bas[15] = -0.5900435899266435f*x*(xx - 3.0f*yy);

        float fv[48];
        const float4* fp = reinterpret_cast<const float4*>(feats + 48*g);
        #pragma unroll
        for (int qq = 0; qq < 12; ++qq)
            *reinterpret_cast<float4*>(&fv[4*qq]) = fp[qq];

        float colr = 0.0f, colg = 0.0f, colb = 0.0f;
        #pragma unroll
        for (int k = 0; k < 16; ++k) {
            colr += bas[k]*fv[k*3+0];
            colg += bas[k]*fv[k*3+1];
            colb += bas[k]*fv[k*3+2];
        }
        colr = fmaxf(colr + 0.5f, 0.0f);
        colg = fmaxf(colg + 0.5f, 0.0f);
        colb = fmaxf(colb + 0.5f, 0.0f);

        SA[rk] = make_float4(cPx[j], cNa[j], cU[j], cV[j]);
        SB[rk] = make_float4(cOp[j], colr, colg, colb);
    }
    __syncthreads();

    // ---------------- phase C: 4-way depth-segmented blend ----------------
    const int q   = tid >> 8;          // sorted-quarter index (wave-uniform)
    const int pix = tid & 255;         // pixel x
    const float fx = (float)pix;
    const int nq = (n + 3) >> 2;
    const int j0 = q*nq;
    const int j1 = min(n, j0 + nq);

    float T = 1.0f, accr = 0.0f, accg = 0.0f, accb = 0.0f;
    for (int j = j0; j < j1; ++j) {
        const float4 A = SA[j];
        const float4 B = SB[j];
        const float dx  = fx - A.x;
        const float pwr = fmaf(fmaf(A.y, dx, A.z), dx, A.w);
        const float gg  = __expf(pwr);
        const float al  = fminf(0.99f, B.x*gg);
        const bool  ok  = (pwr <= 0.0f) && (al >= (1.0f/255.0f));
        const float w   = ok ? al*T : 0.0f;
        accr = fmaf(w, B.y, accr);
        accg = fmaf(w, B.z, accg);
        accb = fmaf(w, B.w, accb);
        T -= w;
    }
    comb[q][pix] = make_float4(accr, accg, accb, T);
    __syncthreads();

    // combine the 4 depth segments front-to-back, add background, store
    if (tid < WW) {
        float Tt = 1.0f, r = 0.0f, g = 0.0f, b = 0.0f;
        #pragma unroll
        for (int s = 0; s < 4; ++s) {
            const float4 c = comb[s][tid];
            r = fmaf(Tt, c.x, r);
            g = fmaf(Tt, c.y, g);
            b = fmaf(Tt, c.z, b);
            Tt *= c.w;
        }
        const int p = blockIdx.x*WW + tid;
        out[p]            = r + Tt;   // bg = 1
        out[HH*WW + p]    = g + Tt;
        out[2*HH*WW + p]  = b + Tt;
    }
}

extern "C" void kernel_launch(void* const* d_in, const int* in_sizes, int n_in,
                              void* d_out, int out_size, void* d_ws, size_t ws_size,
                              hipStream_t stream) {
    const float* means  = (const float*)d_in[0];
    const float* feats  = (const float*)d_in[1];
    const float* opac   = (const float*)d_in[2];
    const float* scales = (const float*)d_in[3];
    const float* rots   = (const float*)d_in[4];
    const float* vm     = (const float*)d_in[5];
    const float* pm     = (const float*)d_in[6];
    const float* campos = (const float*)d_in[7];
    const float* tfx    = (const float*)d_in[8];
    const float* tfy    = (const float*)d_in[9];

    gs_fused_kernel<<<HH, 1024, 0, stream>>>(means, feats, opac, scales, rots, vm, pm,
                                             campos, tfx, tfy, (float*)d_out);
}

// Round 10
// 11.870 us; speedup vs baseline: 5.3872x; 1.0118x over previous
//
#include <hip/hip_runtime.h>
#include <hip/hip_bf16.h>

#define PQ 512
#define HH 256
#define WW 256

// One block per image row, 1024 threads (16 waves/CU).
// Phase A: 1 gaussian/thread geometry + conservative row cull (only drops
//   gaussians with alpha < 1/255 across the whole row) + ballot compaction
//   (prefix computed per-thread from the 8 per-wave counts — no serial scan,
//   one fewer barrier).
// Phase B: rank-sort survivors by global (depth,idx) key (exact stable
//   argsort match) + SH eval for survivors only.
// Phase C: 4-way depth-segmented blend — thread-group q blends sorted
//   quarter q for its pixel; partials combined via T-products in LDS
//   (front-to-back compositing is associative).
__global__ __launch_bounds__(1024) void gs_fused_kernel(
    const float* __restrict__ means, const float* __restrict__ feats,
    const float* __restrict__ opac, const float* __restrict__ scales,
    const float* __restrict__ rots, const float* __restrict__ vm,
    const float* __restrict__ pm, const float* __restrict__ campos,
    const float* __restrict__ tfx, const float* __restrict__ tfy,
    float* __restrict__ out)
{
    __shared__ unsigned long long cKey[PQ];
    __shared__ int   cGi[PQ];
    __shared__ float cPx[PQ], cNa[PQ], cU[PQ], cV[PQ], cOp[PQ];
    __shared__ float4 SA[PQ], SB[PQ];
    __shared__ float4 comb[4][WW];
    __shared__ int s_cnt[8];

    const int tid  = threadIdx.x;
    const int wid  = tid >> 6;
    const int lane = tid & 63;
    const float fy = (float)blockIdx.x;

    const float tanfovx = *tfx, tanfovy = *tfy;
    const float fxs = WW / (2.0f*tanfovx), fys = HH / (2.0f*tanfovy);
    const float limx = 1.3f*tanfovx, limy = 1.3f*tanfovy;

    // ---------------- phase A: per-gaussian geometry + row cull ----------------
    float rPx = 0.f, rNa = 0.f, rU = 0.f, rV = 0.f, rOp = 0.f;
    unsigned long long rKey = 0, m = 0;
    bool kp = false;

    if (tid < PQ) {                       // waves 0..7, wave-uniform branch
        const int g = tid;
        const float mx = means[3*g], my = means[3*g+1], mz = means[3*g+2];

        // view transform
        const float tx = vm[0]*mx + vm[1]*my + vm[2]*mz + vm[3];
        const float ty = vm[4]*mx + vm[5]*my + vm[6]*mz + vm[7];
        const float tz = vm[8]*mx + vm[9]*my + vm[10]*mz + vm[11];
        const float depth = tz;

        // quaternion -> rotation
        const float4 q = *reinterpret_cast<const float4*>(rots + 4*g);
        float qw = q.x, qx = q.y, qy = q.z, qz = q.w;
        const float qn = 1.0f / sqrtf(qw*qw + qx*qx + qy*qy + qz*qz);
        qw *= qn; qx *= qn; qy *= qn; qz *= qn;
        const float R00 = 1.0f - 2.0f*(qy*qy + qz*qz), R01 = 2.0f*(qx*qy - qw*qz), R02 = 2.0f*(qx*qz + qw*qy);
        const float R10 = 2.0f*(qx*qy + qw*qz), R11 = 1.0f - 2.0f*(qx*qx + qz*qz), R12 = 2.0f*(qy*qz - qw*qx);
        const float R20 = 2.0f*(qx*qz - qw*qy), R21 = 2.0f*(qy*qz + qw*qx), R22 = 1.0f - 2.0f*(qx*qx + qy*qy);

        const float s0 = scales[3*g], s1 = scales[3*g+1], s2 = scales[3*g+2];
        const float Sx = s0*s0, Sy = s1*s1, Sz = s2*s2;
        const float c00 = R00*R00*Sx + R01*R01*Sy + R02*R02*Sz;
        const float c01 = R00*R10*Sx + R01*R11*Sy + R02*R12*Sz;
        const float c02 = R00*R20*Sx + R01*R21*Sy + R02*R22*Sz;
        const float c11 = R10*R10*Sx + R11*R11*Sy + R12*R12*Sz;
        const float c12 = R10*R20*Sx + R11*R21*Sy + R12*R22*Sz;
        const float c22 = R20*R20*Sx + R21*R21*Sy + R22*R22*Sz;

        const float invz = 1.0f / tz;
        const float txz = fminf(fmaxf(tx*invz, -limx), limx) * tz;
        const float tyz = fminf(fmaxf(ty*invz, -limy), limy) * tz;
        const float J00 = fxs*invz, J02 = -fxs*txz*invz*invz;
        const float J11 = fys*invz, J12 = -fys*tyz*invz*invz;
        const float T00 = J00*vm[0] + J02*vm[8];
        const float T01 = J00*vm[1] + J02*vm[9];
        const float T02 = J00*vm[2] + J02*vm[10];
        const float T10 = J11*vm[4] + J12*vm[8];
        const float T11 = J11*vm[5] + J12*vm[9];
        const float T12 = J11*vm[6] + J12*vm[10];
        const float u0 = c00*T00 + c01*T01 + c02*T02;
        const float u1 = c01*T00 + c11*T01 + c12*T02;
        const float u2 = c02*T00 + c12*T01 + c22*T02;
        const float v0 = c00*T10 + c01*T11 + c02*T12;
        const float v1 = c01*T10 + c11*T11 + c12*T12;
        const float v2 = c02*T10 + c12*T11 + c22*T12;
        const float a  = T00*u0 + T01*u1 + T02*u2 + 0.3f;
        const float b  = T10*u0 + T11*u1 + T12*u2;
        const float c  = T10*v0 + T11*v1 + T12*v2 + 0.3f;
        const float det = a*c - b*b;
        const bool valid = (depth > 0.2f) && (det > 0.0f);
        const float inv_det = 1.0f / (det > 0.0f ? det : 1.0f);
        const float ca = c*inv_det, cbq = -b*inv_det, cc = a*inv_det;

        // projection
        const float pw = pm[12]*mx + pm[13]*my + pm[14]*mz + pm[15] + 1e-7f;
        const float p0 = pm[0]*mx + pm[1]*my + pm[2]*mz + pm[3];
        const float p1 = pm[4]*mx + pm[5]*my + pm[6]*mz + pm[7];
        const float px = ((p0/pw + 1.0f)*WW - 1.0f)*0.5f;
        const float py = ((p1/pw + 1.0f)*HH - 1.0f)*0.5f;

        const float opa_ = valid ? opac[g] : 0.0f;

        // conservative skip radius (alpha < 1/255 guaranteed outside rmax2)
        const float lmin = 0.25f*(ca + cc) - sqrtf(0.0625f*(ca - cc)*(ca - cc) + 0.25f*cbq*cbq);
        const float thr = __logf(255.0f * opa_);
        float rmax2;
        if (valid && thr > 0.0f)
            rmax2 = (lmin > 0.0f) ? (thr/lmin)*1.02f + 1e-4f : 3.4e38f;
        else
            rmax2 = 0.0f;

        // row cull
        const float dy  = fy - py;
        const float dxn = fmaxf(0.0f, fmaxf(-px, px - (float)(WW-1)));
        kp = (fmaf(dy, dy, dxn*dxn) <= rmax2);

        rPx = px;
        rNa = -0.5f*ca;
        rU  = -cbq*dy;           // nb*dy
        rV  = (-0.5f*cc)*dy*dy;  // nc*dy^2
        rOp = opa_;

        const unsigned int fb = __float_as_uint(depth);
        const unsigned int ks = fb ^ ((fb >> 31) ? 0xFFFFFFFFu : 0x80000000u);
        rKey = ((unsigned long long)ks << 32) | (unsigned int)g;

        m = __ballot(kp);
        if (lane == 0) s_cnt[wid] = __popcll(m);
    }
    __syncthreads();

    // per-thread prefix over the 8 wave counts (no serial scan, no extra barrier)
    int base = 0, ntot = 0;
    #pragma unroll
    for (int w = 0; w < 8; ++w) {
        if (w == wid) base = ntot;
        ntot += s_cnt[w];
    }
    const int n = ntot;

    // scatter survivors into compacted LDS slots
    if (tid < PQ && kp) {
        const int p = base + __popcll(m & ((1ULL << lane) - 1ULL));
        cKey[p] = rKey; cGi[p] = tid;
        cPx[p] = rPx; cNa[p] = rNa; cU[p] = rU; cV[p] = rV; cOp[p] = rOp;
    }
    __syncthreads();

    // ------------- phase B: rank-sort survivors + SH for survivors only -------------
    if (tid < n) {
        const int j = tid;
        const unsigned long long kj = cKey[j];
        int rk = 0;
        for (int i = 0; i < n; ++i) rk += (cKey[i] < kj) ? 1 : 0;

        const int g = cGi[j];
        const float mx = means[3*g], my = means[3*g+1], mz = means[3*g+2];
        const float ddx = mx - campos[0], ddy = my - campos[1], ddz = mz - campos[2];
        const float dn = 1.0f / sqrtf(ddx*ddx + ddy*ddy + ddz*ddz);
        const float x = ddx*dn, y = ddy*dn, z = ddz*dn;
        const float xx = x*x, yy = y*y, zz = z*z, xy = x*y, yz = y*z, xz = x*z;
        float bas[16];
        bas[0]  = 0.28209479177387814f;
        bas[1]  = -0.4886025119029199f*y;
        bas[2]  = 0.4886025119029199f*z;
        bas[3]  = -0.4886025119029199f*x;
        bas[4]  = 1.0925484305920792f*xy;
        bas[5]  = -1.0925484305920792f*yz;
        bas[6]  = 0.31539156525252005f*(2.0f*zz - xx - yy);
        bas[7]  = -1.0925484305920792f*xz;
        bas[8]  = 0.5462742152960396f*(xx - yy);
        bas[9]  = -0.5900435899266435f*y*(3.0f*xx - yy);
        bas[10] = 2.890611442640554f*xy*z;
        bas[11] = -0.4570457994644658f*y*(4.0f*zz - xx - yy);
        bas[12] = 0.3731763325901154f*z*(2.0f*zz - 3.0f*xx - 3.0f*yy);
        bas[13] = -0.4570457994644658f*x*(4.0f*zz - xx - yy);
        bas[14] = 1.445305721320277f*z*(xx - yy);
        bas[15] = -0.5900435899266435f*x*(xx - 3.0f*yy);

        float fv[48];
        const float4* fp = reinterpret_cast<const float4*>(feats + 48*g);
        #pragma unroll
        for (int qq = 0; qq < 12; ++qq)
            *reinterpret_cast<float4*>(&fv[4*qq]) = fp[qq];

        float colr = 0.0f, colg = 0.0f, colb = 0.0f;
        #pragma unroll
        for (int k = 0; k < 16; ++k) {
            colr += bas[k]*fv[k*3+0];
            colg += bas[k]*fv[k*3+1];
            colb += bas[k]*fv[k*3+2];
        }
        colr = fmaxf(colr + 0.5f, 0.0f);
        colg = fmaxf(colg + 0.5f, 0.0f);
        colb = fmaxf(colb + 0.5f, 0.0f);

        SA[rk] = make_float4(cPx[j], cNa[j], cU[j], cV[j]);
        SB[rk] = make_float4(cOp[j], colr, colg, colb);
    }
    __syncthreads();

    // ---------------- phase C: 4-way depth-segmented blend ----------------
    const int q   = tid >> 8;          // sorted-quarter index (wave-uniform)
    const int pix = tid & 255;         // pixel x
    const float fx = (float)pix;
    const int nq = (n + 3) >> 2;
    const int j0 = q*nq;
    const int j1 = min(n, j0 + nq);

    float T = 1.0f, accr = 0.0f, accg = 0.0f, accb = 0.0f;
    #pragma unroll 2
    for (int j = j0; j < j1; ++j) {
        const float4 A = SA[j];
        const float4 B = SB[j];
        const float dx  = fx - A.x;
        const float pwr = fmaf(fmaf(A.y, dx, A.z), dx, A.w);
        const float gg  = __expf(pwr);
        const float al  = fminf(0.99f, B.x*gg);
        const bool  ok  = (pwr <= 0.0f) && (al >= (1.0f/255.0f));
        const float w   = ok ? al*T : 0.0f;
        accr = fmaf(w, B.y, accr);
        accg = fmaf(w, B.z, accg);
        accb = fmaf(w, B.w, accb);
        T -= w;
    }
    comb[q][pix] = make_float4(accr, accg, accb, T);
    __syncthreads();

    // combine the 4 depth segments front-to-back, add background, store
    if (tid < WW) {
        float Tt = 1.0f, r = 0.0f, g = 0.0f, b = 0.0f;
        #pragma unroll
        for (int s = 0; s < 4; ++s) {
            const float4 c = comb[s][tid];
            r = fmaf(Tt, c.x, r);
            g = fmaf(Tt, c.y, g);
            b = fmaf(Tt, c.z, b);
            Tt *= c.w;
        }
        const int p = blockIdx.x*WW + tid;
        out[p]            = r + Tt;   // bg = 1
        out[HH*WW + p]    = g + Tt;
        out[2*HH*WW + p]  = b + Tt;
    }
}

extern "C" void kernel_launch(void* const* d_in, const int* in_sizes, int n_in,
                              void* d_out, int out_size, void* d_ws, size_t ws_size,
                              hipStream_t stream) {
    const float* means  = (const float*)d_in[0];
    const float* feats  = (const float*)d_in[1];
    const float* opac   = (const float*)d_in[2];
    const float* scales = (const float*)d_in[3];
    const float* rots   = (const float*)d_in[4];
    const float* vm     = (const float*)d_in[5];
    const float* pm     = (const float*)d_in[6];
    const float* campos = (const float*)d_in[7];
    const float* tfx    = (const float*)d_in[8];
    const float* tfy    = (const float*)d_in[9];

    gs_fused_kernel<<<HH, 1024, 0, stream>>>(means, feats, opac, scales, rots, vm, pm,
                                             campos, tfx, tfy, (float*)d_out);
}